// Round 1
// baseline (629.897 us; speedup 1.0000x reference)
//
#include <hip/hip_runtime.h>
#include <hip/hip_bf16.h>
#include <math.h>

#define D 256
#define INV_TAU 20.0f
#define CAP 64

typedef __attribute__((ext_vector_type(4))) float f32x4;
typedef __attribute__((ext_vector_type(8))) short bf16x8_t;

__device__ __forceinline__ unsigned short f2bf(float f) {
    union { float f; unsigned u; } v; v.f = f;
    unsigned r = v.u + 0x7FFFu + ((v.u >> 16) & 1u);
    return (unsigned short)(r >> 16);
}

// One wave per row: inverse L2 norm of a 256-dim f32 row.
__global__ void rownorm_kernel(const float* __restrict__ src, float* __restrict__ inv, int rows) {
    int wid = threadIdx.x >> 6;
    int lane = threadIdx.x & 63;
    int row = blockIdx.x * 4 + wid;
    if (row >= rows) return;
    const float4* p = (const float4*)(src + (size_t)row * D);
    float4 v = p[lane];
    float ss = v.x * v.x + v.y * v.y + v.z * v.z + v.w * v.w;
    #pragma unroll
    for (int m = 1; m < 64; m <<= 1) ss += __shfl_xor(ss, m);
    if (lane == 0) inv[row] = 1.0f / sqrtf(ss);
}

// Pass 1: fused que·sen^T/tau -> exp -> row sums (all / pos) + positive-s capture.
// Tile 128(q) x 128(n), 4 waves in 2x2, 16x16x32 bf16 MFMA, K=256 in two 128-halves.
__global__ __launch_bounds__(256)
void qs_pass1(const float* __restrict__ que, const float* __restrict__ sen,
              const float* __restrict__ invq, const float* __restrict__ invn,
              const int* __restrict__ pidq, const int* __restrict__ pidn,
              float* __restrict__ sum_all, float* __restrict__ sum_pos,
              int* __restrict__ cnt, float* __restrict__ pos_s) {
    __shared__ unsigned short As[128 * 128];  // swizzled: idx = row*128 + (c ^ ((row&7)<<3))
    __shared__ unsigned short Bs[128 * 128];
    __shared__ int pqs[128];
    __shared__ int pns[128];

    const int tid = threadIdx.x;
    const int lane = tid & 63;
    const int wid = tid >> 6;
    const int wr = wid >> 1, wc = wid & 1;
    const int n0 = blockIdx.x * 128;
    const int q0 = blockIdx.y * 128;

    if (tid < 128) pqs[tid] = pidq[q0 + tid];
    else           pns[tid - 128] = pidn[n0 + tid - 128];

    f32x4 acc[4][4];
    #pragma unroll
    for (int m = 0; m < 4; ++m)
        #pragma unroll
        for (int n = 0; n < 4; ++n) {
            f32x4 z = {0.f, 0.f, 0.f, 0.f};
            acc[m][n] = z;
        }

    for (int h = 0; h < 2; ++h) {
        const int k0 = h * 128;
        // stage A (que) and B (sen): each 128 rows x 128 k-cols, f32 -> normalized bf16
        #pragma unroll
        for (int i = 0; i < 16; ++i) {
            int slot = i * 256 + tid;        // 0..4095
            int row = slot >> 5;             // 32 float4 slots per row
            int c = (slot & 31) << 2;        // k-col, multiple of 4
            int sidx = row * 128 + (c ^ ((row & 7) << 3));

            float4 va = *(const float4*)(que + (size_t)(q0 + row) * D + k0 + c);
            float sa = invq[q0 + row];
            uint2 pa;
            pa.x = (unsigned)f2bf(va.x * sa) | ((unsigned)f2bf(va.y * sa) << 16);
            pa.y = (unsigned)f2bf(va.z * sa) | ((unsigned)f2bf(va.w * sa) << 16);
            *(uint2*)&As[sidx] = pa;

            float4 vb = *(const float4*)(sen + (size_t)(n0 + row) * D + k0 + c);
            float sb = invn[n0 + row];
            uint2 pb;
            pb.x = (unsigned)f2bf(vb.x * sb) | ((unsigned)f2bf(vb.y * sb) << 16);
            pb.y = (unsigned)f2bf(vb.z * sb) | ((unsigned)f2bf(vb.w * sb) << 16);
            *(uint2*)&Bs[sidx] = pb;
        }
        __syncthreads();
        #pragma unroll
        for (int kk = 0; kk < 4; ++kk) {
            int kc = kk * 32 + (lane >> 4) * 8;
            bf16x8_t af[4], bg[4];
            #pragma unroll
            for (int m = 0; m < 4; ++m) {
                int r = wr * 64 + m * 16 + (lane & 15);
                af[m] = *(const bf16x8_t*)&As[r * 128 + (kc ^ ((r & 7) << 3))];
            }
            #pragma unroll
            for (int n = 0; n < 4; ++n) {
                int r = wc * 64 + n * 16 + (lane & 15);
                bg[n] = *(const bf16x8_t*)&Bs[r * 128 + (kc ^ ((r & 7) << 3))];
            }
            #pragma unroll
            for (int m = 0; m < 4; ++m)
                #pragma unroll
                for (int n = 0; n < 4; ++n)
                    acc[m][n] = __builtin_amdgcn_mfma_f32_16x16x32_bf16(af[m], bg[n], acc[m][n], 0, 0, 0);
        }
        __syncthreads();
    }

    // Epilogue: s = acc*20, e = exp(s); row sums + positive capture.
    const int g = lane >> 4;   // 0..3
    const int cl = lane & 15;
    #pragma unroll
    for (int m = 0; m < 4; ++m) {
        float se[4] = {0.f, 0.f, 0.f, 0.f}, sp[4] = {0.f, 0.f, 0.f, 0.f};
        #pragma unroll
        for (int n = 0; n < 4; ++n) {
            int col = wc * 64 + n * 16 + cl;
            int pcol = pns[col];
            #pragma unroll
            for (int j = 0; j < 4; ++j) {
                int row = wr * 64 + m * 16 + g * 4 + j;
                float s = acc[m][n][j] * INV_TAU;
                float e = __expf(s);
                se[j] += e;
                if (pqs[row] == pcol) {
                    sp[j] += e;
                    int q = q0 + row;
                    int idx = atomicAdd(&cnt[q], 1);
                    if (idx < CAP) pos_s[(size_t)q * CAP + idx] = s;
                }
            }
        }
        #pragma unroll
        for (int j = 0; j < 4; ++j) {
            float a = se[j], b = sp[j];
            #pragma unroll
            for (int msk = 1; msk < 16; msk <<= 1) {
                a += __shfl_xor(a, msk);
                b += __shfl_xor(b, msk);
            }
            if (cl == 0) {
                int q = q0 + wr * 64 + m * 16 + g * 4 + j;
                atomicAdd(&sum_all[q], a);
                if (b != 0.0f) atomicAdd(&sum_pos[q], b);
            }
        }
    }
}

// SQ InfoNCE: one block per section row; sim row cached in LDS; two phases.
__global__ __launch_bounds__(256)
void sq_kernel(const float* __restrict__ sec, const float* __restrict__ que,
               const float* __restrict__ invs, const float* __restrict__ invq,
               const int* __restrict__ secidx, int Q,
               float* __restrict__ scal, int* __restrict__ itot) {
    __shared__ float secl[D];
    __shared__ float sim[4096];
    __shared__ float ra[4], rp[4], rc[4];
    __shared__ int rm[4];
    const int s = blockIdx.x;
    const int tid = threadIdx.x;
    const int lane = tid & 63, wid = tid >> 6;

    secl[tid] = sec[(size_t)s * D + tid] * invs[s];
    __syncthreads();

    float tot_all = 0.f, tot_pos = 0.f;
    int mq = 0;
    for (int q = tid; q < Q; q += 256) {
        const float4* qp = (const float4*)(que + (size_t)q * D);
        float dot = 0.f;
        #pragma unroll 8
        for (int d = 0; d < D / 4; ++d) {
            float4 v = qp[d];
            dot += v.x * secl[d * 4] + v.y * secl[d * 4 + 1] + v.z * secl[d * 4 + 2] + v.w * secl[d * 4 + 3];
        }
        float sv = dot * invq[q] * INV_TAU;
        sim[q] = sv;
        float e = __expf(sv);
        tot_all += e;
        if (secidx[q] == s) { tot_pos += e; mq++; }
    }
    #pragma unroll
    for (int m = 1; m < 64; m <<= 1) {
        tot_all += __shfl_xor(tot_all, m);
        tot_pos += __shfl_xor(tot_pos, m);
        mq += __shfl_xor(mq, m);
    }
    if (lane == 0) { ra[wid] = tot_all; rp[wid] = tot_pos; rm[wid] = mq; }
    __syncthreads();
    float Sa = ra[0] + ra[1] + ra[2] + ra[3];
    float Sp = rp[0] + rp[1] + rp[2] + rp[3];
    int Mq = rm[0] + rm[1] + rm[2] + rm[3];
    float sum_neg = Sa - Sp;

    float contrib = 0.f;
    for (int q = tid; q < Q; q += 256)
        if (secidx[q] == s) { float sv = sim[q]; contrib += sv - __logf(__expf(sv) + sum_neg); }
    #pragma unroll
    for (int m = 1; m < 64; m <<= 1) contrib += __shfl_xor(contrib, m);
    if (lane == 0) rc[wid] = contrib;
    __syncthreads();
    if (tid == 0) {
        float c = rc[0] + rc[1] + rc[2] + rc[3];
        if (Mq > 0 && (Q - Mq) > 0) {
            atomicAdd(&scal[1], c);
            atomicAdd(&itot[1], Mq);
        }
    }
}

// Finish QS: per question compute g, c = Nn*g, and sum of log-ratios over stored positives.
__global__ void finish_qs(const float* __restrict__ sum_all, const float* __restrict__ sum_pos,
                          const int* __restrict__ cnt, const float* __restrict__ pos_s,
                          const int* __restrict__ npptr, int Qn, int Ntot,
                          float* __restrict__ scal, int* __restrict__ itot) {
    int q = blockIdx.x * 256 + threadIdx.x;
    if (q >= Qn) return;
    int M = cnt[q];
    float Sa = sum_all[q], Sp = sum_pos[q];
    float Sn = Sa - Sp;
    int Nn = Ntot - M;
    float Mf = (float)(M > 1 ? M : 1);
    float Nnf = (float)(Nn > 1 ? Nn : 1);
    int P = npptr[0];
    float eta_p = 1.0f / (float)(P > 1 ? P : 1);
    float eta_m = 1.0f - eta_p;
    float minv = __expf(-INV_TAU);
    float gg = (Sn / Nnf - eta_p * Sp / Mf) / eta_m;
    gg = fmaxf(gg, minv);
    float c = (float)Nn * gg;
    int mc = M < CAP ? M : CAP;
    float contrib = 0.f;
    for (int i = 0; i < mc; ++i) {
        float s = pos_s[(size_t)q * CAP + i];
        contrib += s - __logf(__expf(s) + c);
    }
    if (M > 0 && Nn > 0) {
        atomicAdd(&scal[0], contrib);
        atomicAdd(&itot[0], M);
    }
}

__global__ void combine_kernel(const float* __restrict__ scal, const int* __restrict__ itot,
                               float* __restrict__ out) {
    if (threadIdx.x == 0) {
        float qs = itot[0] > 0 ? -scal[0] / (float)itot[0] : 0.0f;
        float sq = itot[1] > 0 ? -scal[1] / (float)itot[1] : 0.0f;
        out[0] = qs + sq;
    }
}

extern "C" void kernel_launch(void* const* d_in, const int* in_sizes, int n_in,
                              void* d_out, int out_size, void* d_ws, size_t ws_size,
                              hipStream_t stream) {
    const float* sec = (const float*)d_in[1];
    const float* que = (const float*)d_in[2];
    const float* sen = (const float*)d_in[3];
    const int* pidq = (const int*)d_in[4];
    const int* sidx = (const int*)d_in[5];
    const int* pidn = (const int*)d_in[6];
    const int* npp = (const int*)d_in[7];
    const int S = in_sizes[1] / D;
    const int Q = in_sizes[2] / D;
    const int N = in_sizes[3] / D;

    float* w = (float*)d_ws;
    float* invq = w; w += Q;
    float* invn = w; w += N;
    float* invs = w; w += S;
    char* zstart = (char*)w;
    float* sum_all = w; w += Q;
    float* sum_pos = w; w += Q;
    int* cnt = (int*)w; w += Q;
    float* scal = w; w += 4;     // [0]=qs_num, [1]=sq_num
    int* itot = (int*)w; w += 4; // [0]=qs_tot, [1]=sq_tot
    size_t zbytes = (char*)w - zstart;
    float* pos_s = w; w += (size_t)Q * CAP;

    hipMemsetAsync(zstart, 0, zbytes, stream);
    rownorm_kernel<<<(Q + 3) / 4, 256, 0, stream>>>(que, invq, Q);
    rownorm_kernel<<<(N + 3) / 4, 256, 0, stream>>>(sen, invn, N);
    rownorm_kernel<<<(S + 3) / 4, 256, 0, stream>>>(sec, invs, S);
    qs_pass1<<<dim3(N / 128, Q / 128), 256, 0, stream>>>(que, sen, invq, invn, pidq, pidn,
                                                         sum_all, sum_pos, cnt, pos_s);
    sq_kernel<<<S, 256, 0, stream>>>(sec, que, invs, invq, sidx, Q, scal, itot);
    finish_qs<<<(Q + 255) / 256, 256, 0, stream>>>(sum_all, sum_pos, cnt, pos_s, npp, Q, N, scal, itot);
    combine_kernel<<<1, 64, 0, stream>>>(scal, itot, (float*)d_out);
}

// Round 2
// 213.899 us; speedup vs baseline: 2.9448x; 2.9448x over previous
//
#include <hip/hip_runtime.h>
#include <hip/hip_bf16.h>
#include <math.h>

#define D 256
#define INV_TAU 20.0f
#define CAP 64

typedef __attribute__((ext_vector_type(4))) float f32x4;
typedef __attribute__((ext_vector_type(8))) short bf16x8_t;

#define GLOAD16(gp, lp) \
    __builtin_amdgcn_global_load_lds((const __attribute__((address_space(1))) void*)(gp), \
                                     (__attribute__((address_space(3))) void*)(lp), 16, 0, 0)

__device__ __forceinline__ unsigned short f2bf(float f) {
    union { float f; unsigned u; } v; v.f = f;
    unsigned r = v.u + 0x7FFFu + ((v.u >> 16) & 1u);
    return (unsigned short)(r >> 16);
}

// Wave per row: normalize a 256-dim f32 row, emit bf16 row (+ optional inv norm).
__global__ void norm2bf16(const float* __restrict__ src, unsigned short* __restrict__ dst,
                          float* __restrict__ inv, int rows) {
    int wid = threadIdx.x >> 6;
    int lane = threadIdx.x & 63;
    int row = blockIdx.x * 4 + wid;
    if (row >= rows) return;
    const float4* p = (const float4*)(src + (size_t)row * D);
    float4 v = p[lane];
    float ss = v.x * v.x + v.y * v.y + v.z * v.z + v.w * v.w;
    #pragma unroll
    for (int m = 1; m < 64; m <<= 1) ss += __shfl_xor(ss, m);
    float r = rsqrtf(ss);
    if (inv && lane == 0) inv[row] = r;
    ushort4 o;
    o.x = f2bf(v.x * r); o.y = f2bf(v.y * r); o.z = f2bf(v.z * r); o.w = f2bf(v.w * r);
    *(ushort4*)(dst + (size_t)row * D + lane * 4) = o;
}

// Wave per row: normalized f32 row (for sections).
__global__ void normf32(const float* __restrict__ src, float* __restrict__ dst, int rows) {
    int wid = threadIdx.x >> 6;
    int lane = threadIdx.x & 63;
    int row = blockIdx.x * 4 + wid;
    if (row >= rows) return;
    const float4* p = (const float4*)(src + (size_t)row * D);
    float4 v = p[lane];
    float ss = v.x * v.x + v.y * v.y + v.z * v.z + v.w * v.w;
    #pragma unroll
    for (int m = 1; m < 64; m <<= 1) ss += __shfl_xor(ss, m);
    float r = rsqrtf(ss);
    float4 o; o.x = v.x * r; o.y = v.y * r; o.z = v.z * r; o.w = v.w * r;
    *(float4*)(dst + (size_t)row * D + lane * 4) = o;
}

// Pass 1: fused que·sen^T/tau -> exp -> row sums + positive-s capture.
// 128x128 tile, BK=64, 4 waves 2x2. bf16 inputs pre-normalized.
// LDS [128][64] bf16, linear dest for global_load_lds; 16B-chunk swizzle
// (c ^= row&7) applied on the SOURCE address and again on the ds_read side.
__global__ __launch_bounds__(256)
void qs_pass1(const unsigned short* __restrict__ queb, const unsigned short* __restrict__ senb,
              const int* __restrict__ pidq, const int* __restrict__ pidn,
              float* __restrict__ sum_all, float* __restrict__ sum_pos,
              int* __restrict__ cnt, float* __restrict__ pos_s) {
    __shared__ unsigned short As[128 * 64];
    __shared__ unsigned short Bs[128 * 64];
    __shared__ int pqs[128];
    __shared__ int pns[128];

    const int tid = threadIdx.x;
    const int lane = tid & 63;
    const int wid = tid >> 6;
    const int wr = wid >> 1, wc = wid & 1;
    const int n0 = blockIdx.x * 128;
    const int q0 = blockIdx.y * 128;

    if (tid < 128) pqs[tid] = pidq[q0 + tid];
    else           pns[tid - 128] = pidn[n0 + tid - 128];

    f32x4 acc[4][4];
    #pragma unroll
    for (int m = 0; m < 4; ++m)
        #pragma unroll
        for (int n = 0; n < 4; ++n) {
            f32x4 z = {0.f, 0.f, 0.f, 0.f};
            acc[m][n] = z;
        }

    // Hoist per-lane staging source addresses (k0 added per step).
    const unsigned short* qa[4];
    const unsigned short* sb[4];
    unsigned ldsoff[4];
    #pragma unroll
    for (int j = 0; j < 4; ++j) {
        int cid = (wid * 4 + j) * 64 + lane;     // 16B-chunk id, 0..1023
        int row = cid >> 3;                       // tile row
        int c = cid & 7;                          // chunk within row
        int sc = ((c ^ (row & 7)) << 3);          // swizzled element offset in row
        qa[j] = queb + (size_t)(q0 + row) * D + sc;
        sb[j] = senb + (size_t)(n0 + row) * D + sc;
        ldsoff[j] = (wid * 4 + j) * 512;          // elements (wave-uniform)
    }

    for (int ks = 0; ks < 4; ++ks) {
        const int k0 = ks * 64;
        #pragma unroll
        for (int j = 0; j < 4; ++j) {
            GLOAD16(qa[j] + k0, &As[ldsoff[j]]);
            GLOAD16(sb[j] + k0, &Bs[ldsoff[j]]);
        }
        __syncthreads();
        #pragma unroll
        for (int kk = 0; kk < 2; ++kk) {
            bf16x8_t af[4], bg[4];
            #pragma unroll
            for (int m = 0; m < 4; ++m) {
                int r = wr * 64 + m * 16 + (lane & 15);
                int ch = (kk * 4 + (lane >> 4)) ^ (r & 7);
                af[m] = *(const bf16x8_t*)&As[r * 64 + ch * 8];
            }
            #pragma unroll
            for (int n = 0; n < 4; ++n) {
                int r = wc * 64 + n * 16 + (lane & 15);
                int ch = (kk * 4 + (lane >> 4)) ^ (r & 7);
                bg[n] = *(const bf16x8_t*)&Bs[r * 64 + ch * 8];
            }
            #pragma unroll
            for (int m = 0; m < 4; ++m)
                #pragma unroll
                for (int n = 0; n < 4; ++n)
                    acc[m][n] = __builtin_amdgcn_mfma_f32_16x16x32_bf16(af[m], bg[n], acc[m][n], 0, 0, 0);
        }
        __syncthreads();
    }

    // Epilogue: s = acc*20, e = exp(s); row sums + positive capture.
    const int g = lane >> 4;
    const int cl = lane & 15;
    #pragma unroll
    for (int m = 0; m < 4; ++m) {
        float se[4] = {0.f, 0.f, 0.f, 0.f}, sp[4] = {0.f, 0.f, 0.f, 0.f};
        #pragma unroll
        for (int n = 0; n < 4; ++n) {
            int col = wc * 64 + n * 16 + cl;
            int pcol = pns[col];
            #pragma unroll
            for (int j = 0; j < 4; ++j) {
                int row = wr * 64 + m * 16 + g * 4 + j;
                float s = acc[m][n][j] * INV_TAU;
                float e = __expf(s);
                se[j] += e;
                if (pqs[row] == pcol) {
                    sp[j] += e;
                    int q = q0 + row;
                    int idx = atomicAdd(&cnt[q], 1);
                    if (idx < CAP) pos_s[(size_t)q * CAP + idx] = s;
                }
            }
        }
        #pragma unroll
        for (int j = 0; j < 4; ++j) {
            float a = se[j], b = sp[j];
            #pragma unroll
            for (int msk = 1; msk < 16; msk <<= 1) {
                a += __shfl_xor(a, msk);
                b += __shfl_xor(b, msk);
            }
            if (cl == 0) {
                int q = q0 + wr * 64 + m * 16 + g * 4 + j;
                atomicAdd(&sum_all[q], a);
                if (b != 0.0f) atomicAdd(&sum_pos[q], b);
            }
        }
    }
}

// SQ phase A: grid (Q/256, S). Per-block partial exp-sums per section + sim for positives.
__global__ __launch_bounds__(256)
void sq_partial(const float* __restrict__ que, const float* __restrict__ invq,
                const float* __restrict__ secn, const int* __restrict__ secidx,
                int Q, float* __restrict__ simq,
                float* __restrict__ sq_all, float* __restrict__ sq_pos, int* __restrict__ sq_m) {
    __shared__ float secl[D];
    __shared__ float ra[4], rp[4];
    __shared__ int rm[4];
    const int s = blockIdx.y;
    const int tid = threadIdx.x;
    const int lane = tid & 63, wid = tid >> 6;
    const int q = blockIdx.x * 256 + tid;

    secl[tid] = secn[(size_t)s * D + tid];
    __syncthreads();

    const float4* qp = (const float4*)(que + (size_t)q * D);
    float dot = 0.f;
    #pragma unroll 16
    for (int d = 0; d < D / 4; ++d) {
        float4 v = qp[d];
        dot += v.x * secl[d * 4] + v.y * secl[d * 4 + 1] + v.z * secl[d * 4 + 2] + v.w * secl[d * 4 + 3];
    }
    float sv = dot * invq[q] * INV_TAU;
    float e = __expf(sv);
    bool pos = (secidx[q] == s);
    if (pos) simq[q] = sv;
    float tp = pos ? e : 0.f;
    int mq = pos ? 1 : 0;
    #pragma unroll
    for (int m = 1; m < 64; m <<= 1) {
        e += __shfl_xor(e, m);
        tp += __shfl_xor(tp, m);
        mq += __shfl_xor(mq, m);
    }
    if (lane == 0) { ra[wid] = e; rp[wid] = tp; rm[wid] = mq; }
    __syncthreads();
    if (tid == 0) {
        atomicAdd(&sq_all[s], ra[0] + ra[1] + ra[2] + ra[3]);
        atomicAdd(&sq_pos[s], rp[0] + rp[1] + rp[2] + rp[3]);
        atomicAdd(&sq_m[s], rm[0] + rm[1] + rm[2] + rm[3]);
    }
}

// SQ phase B: per-question positive term.
__global__ void sq_finish(const int* __restrict__ secidx, const float* __restrict__ simq,
                          const float* __restrict__ sq_all, const float* __restrict__ sq_pos,
                          const int* __restrict__ sq_m, int Q,
                          float* __restrict__ scal, int* __restrict__ itot) {
    __shared__ float rc[4];
    __shared__ int rn[4];
    int tid = threadIdx.x;
    int q = blockIdx.x * 256 + tid;
    int lane = tid & 63, wid = tid >> 6;
    float contrib = 0.f;
    int c1 = 0;
    if (q < Q) {
        int s = secidx[q];
        int Mq = sq_m[s];
        if (Mq > 0 && (Q - Mq) > 0) {
            float sumneg = sq_all[s] - sq_pos[s];
            float sv = simq[q];
            contrib = sv - __logf(__expf(sv) + sumneg);
            c1 = 1;
        }
    }
    #pragma unroll
    for (int m = 1; m < 64; m <<= 1) {
        contrib += __shfl_xor(contrib, m);
        c1 += __shfl_xor(c1, m);
    }
    if (lane == 0) { rc[wid] = contrib; rn[wid] = c1; }
    __syncthreads();
    if (tid == 0) {
        atomicAdd(&scal[1], rc[0] + rc[1] + rc[2] + rc[3]);
        atomicAdd(&itot[1], rn[0] + rn[1] + rn[2] + rn[3]);
    }
}

// Finish QS: per question compute g, c = Nn*g, sum log-ratios over stored positives.
__global__ void finish_qs(const float* __restrict__ sum_all, const float* __restrict__ sum_pos,
                          const int* __restrict__ cnt, const float* __restrict__ pos_s,
                          const int* __restrict__ npptr, int Qn, int Ntot,
                          float* __restrict__ scal, int* __restrict__ itot) {
    int q = blockIdx.x * 256 + threadIdx.x;
    if (q >= Qn) return;
    int M = cnt[q];
    float Sa = sum_all[q], Sp = sum_pos[q];
    float Sn = Sa - Sp;
    int Nn = Ntot - M;
    float Mf = (float)(M > 1 ? M : 1);
    float Nnf = (float)(Nn > 1 ? Nn : 1);
    int P = npptr[0];
    float eta_p = 1.0f / (float)(P > 1 ? P : 1);
    float eta_m = 1.0f - eta_p;
    float minv = __expf(-INV_TAU);
    float gg = (Sn / Nnf - eta_p * Sp / Mf) / eta_m;
    gg = fmaxf(gg, minv);
    float c = (float)Nn * gg;
    int mc = M < CAP ? M : CAP;
    float contrib = 0.f;
    for (int i = 0; i < mc; ++i) {
        float s = pos_s[(size_t)q * CAP + i];
        contrib += s - __logf(__expf(s) + c);
    }
    if (M > 0 && Nn > 0) {
        atomicAdd(&scal[0], contrib);
        atomicAdd(&itot[0], M);
    }
}

__global__ void combine_kernel(const float* __restrict__ scal, const int* __restrict__ itot,
                               float* __restrict__ out) {
    if (threadIdx.x == 0) {
        float qs = itot[0] > 0 ? -scal[0] / (float)itot[0] : 0.0f;
        float sq = itot[1] > 0 ? -scal[1] / (float)itot[1] : 0.0f;
        out[0] = qs + sq;
    }
}

extern "C" void kernel_launch(void* const* d_in, const int* in_sizes, int n_in,
                              void* d_out, int out_size, void* d_ws, size_t ws_size,
                              hipStream_t stream) {
    const float* sec = (const float*)d_in[1];
    const float* que = (const float*)d_in[2];
    const float* sen = (const float*)d_in[3];
    const int* pidq = (const int*)d_in[4];
    const int* sidx = (const int*)d_in[5];
    const int* pidn = (const int*)d_in[6];
    const int* npp = (const int*)d_in[7];
    const int S = in_sizes[1] / D;
    const int Q = in_sizes[2] / D;
    const int N = in_sizes[3] / D;

    char* p = (char*)d_ws;
    unsigned short* queb = (unsigned short*)p; p += (size_t)Q * D * 2;
    unsigned short* senb = (unsigned short*)p; p += (size_t)N * D * 2;
    float* invq = (float*)p; p += (size_t)Q * 4;
    float* secn = (float*)p; p += (size_t)S * D * 4;
    float* simq = (float*)p; p += (size_t)Q * 4;
    float* pos_s = (float*)p; p += (size_t)Q * CAP * 4;
    char* z0 = p;
    float* sum_all = (float*)p; p += (size_t)Q * 4;
    float* sum_pos = (float*)p; p += (size_t)Q * 4;
    int* cnt = (int*)p; p += (size_t)Q * 4;
    float* sq_all = (float*)p; p += (size_t)S * 4;
    float* sq_pos = (float*)p; p += (size_t)S * 4;
    int* sq_m = (int*)p; p += (size_t)S * 4;
    float* scal = (float*)p; p += 16;
    int* itot = (int*)p; p += 16;
    size_t zbytes = (size_t)(p - z0);

    hipMemsetAsync(z0, 0, zbytes, stream);
    norm2bf16<<<(Q + 3) / 4, 256, 0, stream>>>(que, queb, invq, Q);
    norm2bf16<<<(N + 3) / 4, 256, 0, stream>>>(sen, senb, nullptr, N);
    normf32<<<(S + 3) / 4, 256, 0, stream>>>(sec, secn, S);
    qs_pass1<<<dim3(N / 128, Q / 128), 256, 0, stream>>>(queb, senb, pidq, pidn,
                                                         sum_all, sum_pos, cnt, pos_s);
    sq_partial<<<dim3(Q / 256, S), 256, 0, stream>>>(que, invq, secn, sidx, Q, simq,
                                                     sq_all, sq_pos, sq_m);
    finish_qs<<<(Q + 255) / 256, 256, 0, stream>>>(sum_all, sum_pos, cnt, pos_s, npp, Q, N, scal, itot);
    sq_finish<<<(Q + 255) / 256, 256, 0, stream>>>(sidx, simq, sq_all, sq_pos, sq_m, Q, scal, itot);
    combine_kernel<<<1, 64, 0, stream>>>(scal, itot, (float*)d_out);
}

// Round 3
// 181.024 us; speedup vs baseline: 3.4796x; 1.1816x over previous
//
#include <hip/hip_runtime.h>
#include <hip/hip_bf16.h>
#include <math.h>

#define D 256
#define INV_TAU 20.0f
#define CAP 64
#define PBUF 128

typedef __attribute__((ext_vector_type(4))) float f32x4;
typedef __attribute__((ext_vector_type(8))) short bf16x8_t;

#define GLOAD16(gp, lp) \
    __builtin_amdgcn_global_load_lds((const __attribute__((address_space(1))) void*)(gp), \
                                     (__attribute__((address_space(3))) void*)(lp), 16, 0, 0)

__device__ __forceinline__ unsigned short f2bf(float f) {
    union { float f; unsigned u; } v; v.f = f;
    unsigned r = v.u + 0x7FFFu + ((v.u >> 16) & 1u);
    return (unsigned short)(r >> 16);
}

// Wave per row: L2-normalize a 256-dim f32 row into bf16.
__global__ void norm2bf16(const float* __restrict__ src, unsigned short* __restrict__ dst, int rows) {
    int wid = threadIdx.x >> 6;
    int lane = threadIdx.x & 63;
    int row = blockIdx.x * 4 + wid;
    if (row >= rows) return;
    const float4* p = (const float4*)(src + (size_t)row * D);
    float4 v = p[lane];
    float ss = v.x * v.x + v.y * v.y + v.z * v.z + v.w * v.w;
    #pragma unroll
    for (int m = 1; m < 64; m <<= 1) ss += __shfl_xor(ss, m);
    float r = rsqrtf(ss);
    ushort4 o;
    o.x = f2bf(v.x * r); o.y = f2bf(v.y * r); o.z = f2bf(v.z * r); o.w = f2bf(v.w * r);
    *(ushort4*)(dst + (size_t)row * D + lane * 4) = o;
}

// QS pass 1: que·sen^T/tau -> exp -> per-block row-sum partials + LDS-buffered positive capture.
// 128x128 tile, BK=64 double-buffered, counted vmcnt + raw barriers (T3/T4 minimum pipeline).
__global__ __launch_bounds__(256)
void qs_pass1(const unsigned short* __restrict__ queb, const unsigned short* __restrict__ senb,
              const int* __restrict__ pidq, const int* __restrict__ pidn, int Q,
              float* __restrict__ partial, int* __restrict__ cnt, float* __restrict__ pos_s) {
    __shared__ unsigned short As[2][128 * 64];
    __shared__ unsigned short Bs[2][128 * 64];
    __shared__ int pqs[128];
    __shared__ int pns[128];
    __shared__ float sums[2][128];
    __shared__ int lcnt;
    __shared__ int lq[PBUF];
    __shared__ float lsv[PBUF];

    const int tid = threadIdx.x;
    const int lane = tid & 63;
    const int wid = tid >> 6;
    const int wr = wid >> 1, wc = wid & 1;
    const int n0 = blockIdx.x * 128;
    const int q0 = blockIdx.y * 128;

    if (tid < 128) pqs[tid] = pidq[q0 + tid];
    else           pns[tid - 128] = pidn[n0 + tid - 128];
    if (tid == 0) lcnt = 0;
    __syncthreads();   // drains pid loads: clean vmcnt before counted waits

    // Staging geometry: chunk cid0 = wid*256+lane (j adds 8 rows). Source pre-swizzled,
    // LDS linear (rule #21). sc constant across j since j*8 rows keeps (row&7) xor bits.
    const int cid0 = wid * 256 + lane;
    const int row0 = cid0 >> 3;
    const int c0 = cid0 & 7;
    const int sc = (c0 ^ (row0 & 7)) << 3;
    const unsigned short* qa = queb + (size_t)(q0 + row0) * D + sc;
    const unsigned short* sb = senb + (size_t)(n0 + row0) * D + sc;
    const int ldsA = wid * 2048;   // wave-uniform; HW adds lane*16B

#define STAGE(buf, k0) do { \
    _Pragma("unroll") \
    for (int j_ = 0; j_ < 4; ++j_) { \
        GLOAD16(qa + (k0) + j_ * 8 * D, &As[buf][ldsA + j_ * 512]); \
        GLOAD16(sb + (k0) + j_ * 8 * D, &Bs[buf][ldsA + j_ * 512]); \
    } } while (0)

    f32x4 acc[4][4];
    #pragma unroll
    for (int m = 0; m < 4; ++m)
        #pragma unroll
        for (int n = 0; n < 4; ++n)
            acc[m][n] = (f32x4){0.f, 0.f, 0.f, 0.f};

    STAGE(0, 0);
    #pragma unroll
    for (int ks = 0; ks < 4; ++ks) {
        const int cur = ks & 1;
        if (ks < 3) {
            STAGE(cur ^ 1, (ks + 1) * 64);
            asm volatile("s_waitcnt vmcnt(8)" ::: "memory");
        } else {
            asm volatile("s_waitcnt vmcnt(0)" ::: "memory");
        }
        __builtin_amdgcn_s_barrier();
        #pragma unroll
        for (int kk = 0; kk < 2; ++kk) {
            bf16x8_t af[4], bg[4];
            #pragma unroll
            for (int m = 0; m < 4; ++m) {
                int r = wr * 64 + m * 16 + (lane & 15);
                int ch = (kk * 4 + (lane >> 4)) ^ (r & 7);
                af[m] = *(const bf16x8_t*)&As[cur][r * 64 + ch * 8];
            }
            #pragma unroll
            for (int n = 0; n < 4; ++n) {
                int r = wc * 64 + n * 16 + (lane & 15);
                int ch = (kk * 4 + (lane >> 4)) ^ (r & 7);
                bg[n] = *(const bf16x8_t*)&Bs[cur][r * 64 + ch * 8];
            }
            #pragma unroll
            for (int m = 0; m < 4; ++m)
                #pragma unroll
                for (int n = 0; n < 4; ++n)
                    acc[m][n] = __builtin_amdgcn_mfma_f32_16x16x32_bf16(af[m], bg[n], acc[m][n], 0, 0, 0);
        }
        if (ks < 3) __builtin_amdgcn_s_barrier();
    }
#undef STAGE

    // Epilogue: exp + row partial sums (no global atomics) + LDS positive capture.
    const int g = lane >> 4;
    const int cl = lane & 15;
    #pragma unroll
    for (int m = 0; m < 4; ++m) {
        float se[4] = {0.f, 0.f, 0.f, 0.f};
        #pragma unroll
        for (int n = 0; n < 4; ++n) {
            const int col = wc * 64 + n * 16 + cl;
            const int pcol = pns[col];
            #pragma unroll
            for (int j = 0; j < 4; ++j) {
                const int row = wr * 64 + m * 16 + g * 4 + j;
                float s = acc[m][n][j] * INV_TAU;
                float e = __expf(s);
                se[j] += e;
                if (pqs[row] == pcol) {
                    int li = atomicAdd(&lcnt, 1);   // LDS atomic, ~30 cyc
                    if (li < PBUF) { lq[li] = q0 + row; lsv[li] = s; }
                }
            }
        }
        #pragma unroll
        for (int j = 0; j < 4; ++j) {
            float a = se[j];
            #pragma unroll
            for (int msk = 1; msk < 16; msk <<= 1) a += __shfl_xor(a, msk);
            if (cl == 0) sums[wc][wr * 64 + m * 16 + g * 4 + j] = a;
        }
    }
    __syncthreads();
    if (tid < 128)
        partial[(size_t)blockIdx.x * Q + q0 + tid] = sums[0][tid] + sums[1][tid];
    int nc = lcnt < PBUF ? lcnt : PBUF;
    for (int i = tid; i < nc; i += 256) {
        int q = lq[i];
        int idx = atomicAdd(&cnt[q], 1);
        if (idx < CAP) pos_s[(size_t)q * CAP + idx] = lsv[i];
    }
}

// SQ via MFMA: grid Q/128 blocks; each block computes all 64 sections x 128 questions.
// secb staged once (32KB); queb tile staged in two 128-K halves (32KB).
__global__ __launch_bounds__(256)
void sq_mfma(const unsigned short* __restrict__ secb, const unsigned short* __restrict__ queb,
             const int* __restrict__ sidx,
             float* __restrict__ sq_all, float* __restrict__ sq_pos, int* __restrict__ sq_m,
             float* __restrict__ simq) {
    __shared__ unsigned short Asq[64 * 256];
    __shared__ unsigned short Bsq[128 * 128];
    const int tid = threadIdx.x;
    const int lane = tid & 63;
    const int wid = tid >> 6;
    const int q0 = blockIdx.x * 128;

    // Stage A (sec, full K): 2048 chunks, 8/thread; pre-swizzled source, linear LDS.
    #pragma unroll
    for (int j = 0; j < 8; ++j) {
        int cid = j * 256 + tid;
        int row = cid >> 5, c = cid & 31;
        int scc = (c ^ (row & 15)) << 3;
        GLOAD16(secb + (size_t)row * D + scc, &Asq[j * 2048 + wid * 512]);
    }

    f32x4 acc[4][2];
    #pragma unroll
    for (int si = 0; si < 4; ++si)
        #pragma unroll
        for (int qi = 0; qi < 2; ++qi)
            acc[si][qi] = (f32x4){0.f, 0.f, 0.f, 0.f};

    for (int h = 0; h < 2; ++h) {
        if (h) __syncthreads();
        #pragma unroll
        for (int j = 0; j < 8; ++j) {
            int cid = j * 256 + tid;
            int row = cid >> 4, c = cid & 15;   // 16 chunks per 128-elem half-row
            int scc = (c ^ (row & 15)) << 3;
            GLOAD16(queb + (size_t)(q0 + row) * D + h * 128 + scc, &Bsq[j * 2048 + wid * 512]);
        }
        __syncthreads();
        #pragma unroll
        for (int kk = 0; kk < 4; ++kk) {
            bf16x8_t af[4], bq[2];
            #pragma unroll
            for (int si = 0; si < 4; ++si) {
                int r = si * 16 + (lane & 15);
                int ch = (h * 16 + kk * 4 + (lane >> 4)) ^ (r & 15);
                af[si] = *(const bf16x8_t*)&Asq[r * 256 + ch * 8];
            }
            #pragma unroll
            for (int qi = 0; qi < 2; ++qi) {
                int r = wid * 32 + qi * 16 + (lane & 15);
                int ch = (kk * 4 + (lane >> 4)) ^ (r & 15);
                bq[qi] = *(const bf16x8_t*)&Bsq[r * 128 + ch * 8];
            }
            #pragma unroll
            for (int si = 0; si < 4; ++si)
                #pragma unroll
                for (int qi = 0; qi < 2; ++qi)
                    acc[si][qi] = __builtin_amdgcn_mfma_f32_16x16x32_bf16(af[si], bq[qi], acc[si][qi], 0, 0, 0);
        }
    }

    const int g = lane >> 4;
    const int cl = lane & 15;
    int sidxv[2];
    sidxv[0] = sidx[q0 + wid * 32 + cl];
    sidxv[1] = sidx[q0 + wid * 32 + 16 + cl];
    #pragma unroll
    for (int si = 0; si < 4; ++si) {
        float pa[4] = {0.f, 0.f, 0.f, 0.f};
        #pragma unroll
        for (int qi = 0; qi < 2; ++qi) {
            #pragma unroll
            for (int j = 0; j < 4; ++j) {
                int srow = si * 16 + g * 4 + j;
                float sv = acc[si][qi][j] * INV_TAU;
                float e = __expf(sv);
                pa[j] += e;
                if (sidxv[qi] == srow) {
                    int q = q0 + wid * 32 + qi * 16 + cl;
                    simq[q] = sv;
                    atomicAdd(&sq_pos[srow], e);
                    atomicAdd(&sq_m[srow], 1);
                }
            }
        }
        #pragma unroll
        for (int j = 0; j < 4; ++j) {
            float a = pa[j];
            #pragma unroll
            for (int msk = 1; msk < 16; msk <<= 1) a += __shfl_xor(a, msk);
            if (cl == 0) atomicAdd(&sq_all[si * 16 + g * 4 + j], a);
        }
    }
}

// Finish QS: reduce row-sum partials, recompute Sp from captured s, g, contribs.
__global__ void finish_qs(const float* __restrict__ partial, int NB,
                          const int* __restrict__ cnt, const float* __restrict__ pos_s,
                          const int* __restrict__ npptr, int Qn, int Ntot,
                          float* __restrict__ scal, int* __restrict__ itot) {
    int q = blockIdx.x * 256 + threadIdx.x;
    if (q >= Qn) return;
    float Sa = 0.f;
    for (int nb = 0; nb < NB; ++nb) Sa += partial[(size_t)nb * Qn + q];
    int M = cnt[q];
    int mc = M < CAP ? M : CAP;
    float Sp = 0.f;
    for (int i = 0; i < mc; ++i) Sp += __expf(pos_s[(size_t)q * CAP + i]);
    float Sn = Sa - Sp;
    int Nn = Ntot - M;
    float Mf = (float)(M > 1 ? M : 1);
    float Nnf = (float)(Nn > 1 ? Nn : 1);
    int P = npptr[0];
    float eta_p = 1.0f / (float)(P > 1 ? P : 1);
    float eta_m = 1.0f - eta_p;
    float minv = __expf(-INV_TAU);
    float gg = (Sn / Nnf - eta_p * Sp / Mf) / eta_m;
    gg = fmaxf(gg, minv);
    float c = (float)Nn * gg;
    float contrib = 0.f;
    for (int i = 0; i < mc; ++i) {
        float s = pos_s[(size_t)q * CAP + i];
        contrib += s - __logf(__expf(s) + c);
    }
    if (M > 0 && Nn > 0) {
        atomicAdd(&scal[0], contrib);
        atomicAdd(&itot[0], M);
    }
}

__global__ void sq_finish(const int* __restrict__ secidx, const float* __restrict__ simq,
                          const float* __restrict__ sq_all, const float* __restrict__ sq_pos,
                          const int* __restrict__ sq_m, int Q,
                          float* __restrict__ scal, int* __restrict__ itot) {
    __shared__ float rc[4];
    __shared__ int rn[4];
    int tid = threadIdx.x;
    int q = blockIdx.x * 256 + tid;
    int lane = tid & 63, wid = tid >> 6;
    float contrib = 0.f;
    int c1 = 0;
    if (q < Q) {
        int s = secidx[q];
        int Mq = sq_m[s];
        if (Mq > 0 && (Q - Mq) > 0) {
            float sumneg = sq_all[s] - sq_pos[s];
            float sv = simq[q];
            contrib = sv - __logf(__expf(sv) + sumneg);
            c1 = 1;
        }
    }
    #pragma unroll
    for (int m = 1; m < 64; m <<= 1) {
        contrib += __shfl_xor(contrib, m);
        c1 += __shfl_xor(c1, m);
    }
    if (lane == 0) { rc[wid] = contrib; rn[wid] = c1; }
    __syncthreads();
    if (tid == 0) {
        atomicAdd(&scal[1], rc[0] + rc[1] + rc[2] + rc[3]);
        atomicAdd(&itot[1], rn[0] + rn[1] + rn[2] + rn[3]);
    }
}

__global__ void combine_kernel(const float* __restrict__ scal, const int* __restrict__ itot,
                               float* __restrict__ out) {
    if (threadIdx.x == 0) {
        float qs = itot[0] > 0 ? -scal[0] / (float)itot[0] : 0.0f;
        float sq = itot[1] > 0 ? -scal[1] / (float)itot[1] : 0.0f;
        out[0] = qs + sq;
    }
}

extern "C" void kernel_launch(void* const* d_in, const int* in_sizes, int n_in,
                              void* d_out, int out_size, void* d_ws, size_t ws_size,
                              hipStream_t stream) {
    const float* sec = (const float*)d_in[1];
    const float* que = (const float*)d_in[2];
    const float* sen = (const float*)d_in[3];
    const int* pidq = (const int*)d_in[4];
    const int* sidx = (const int*)d_in[5];
    const int* pidn = (const int*)d_in[6];
    const int* npp = (const int*)d_in[7];
    const int S = in_sizes[1] / D;
    const int Q = in_sizes[2] / D;
    const int N = in_sizes[3] / D;
    const int NB = N / 128;

    char* p = (char*)d_ws;
    unsigned short* queb = (unsigned short*)p; p += (size_t)Q * D * 2;
    unsigned short* senb = (unsigned short*)p; p += (size_t)N * D * 2;
    unsigned short* secb = (unsigned short*)p; p += (size_t)S * D * 2;
    float* simq = (float*)p; p += (size_t)Q * 4;
    float* pos_s = (float*)p; p += (size_t)Q * CAP * 4;
    float* partial = (float*)p; p += (size_t)NB * Q * 4;
    char* z0 = p;
    int* cnt = (int*)p; p += (size_t)Q * 4;
    float* sq_all = (float*)p; p += (size_t)S * 4;
    float* sq_pos = (float*)p; p += (size_t)S * 4;
    int* sq_m = (int*)p; p += (size_t)S * 4;
    float* scal = (float*)p; p += 16;
    int* itot = (int*)p; p += 16;
    size_t zbytes = (size_t)(p - z0);

    hipMemsetAsync(z0, 0, zbytes, stream);
    norm2bf16<<<(Q + 3) / 4, 256, 0, stream>>>(que, queb, Q);
    norm2bf16<<<(N + 3) / 4, 256, 0, stream>>>(sen, senb, N);
    norm2bf16<<<(S + 3) / 4, 256, 0, stream>>>(sec, secb, S);
    qs_pass1<<<dim3(NB, Q / 128), 256, 0, stream>>>(queb, senb, pidq, pidn, Q,
                                                    partial, cnt, pos_s);
    sq_mfma<<<Q / 128, 256, 0, stream>>>(secb, queb, sidx, sq_all, sq_pos, sq_m, simq);
    finish_qs<<<(Q + 255) / 256, 256, 0, stream>>>(partial, NB, cnt, pos_s, npp, Q, N, scal, itot);
    sq_finish<<<(Q + 255) / 256, 256, 0, stream>>>(sidx, simq, sq_all, sq_pos, sq_m, Q, scal, itot);
    combine_kernel<<<1, 64, 0, stream>>>(scal, itot, (float*)d_out);
}

// Round 4
// 100.567 us; speedup vs baseline: 6.2635x; 1.8000x over previous
//
#include <hip/hip_runtime.h>
#include <hip/hip_bf16.h>
#include <math.h>

#define D 256
#define INV_TAU 20.0f
#define CAP 64
#define PBUF 128

typedef __attribute__((ext_vector_type(4))) float f32x4;
typedef __attribute__((ext_vector_type(8))) short bf16x8_t;

#define GLOAD16(gp, lp) \
    __builtin_amdgcn_global_load_lds((const __attribute__((address_space(1))) void*)(gp), \
                                     (__attribute__((address_space(3))) void*)(lp), 16, 0, 0)

__device__ __forceinline__ unsigned short f2bf(float f) {
    union { float f; unsigned u; } v; v.f = f;
    unsigned r = v.u + 0x7FFFu + ((v.u >> 16) & 1u);
    return (unsigned short)(r >> 16);
}

// Fused: L2-normalize every row of que/sen/sec into bf16. Wave per row.
__global__ void norm_all(const float* __restrict__ que, const float* __restrict__ sen,
                         const float* __restrict__ sec,
                         unsigned short* __restrict__ queb, unsigned short* __restrict__ senb,
                         unsigned short* __restrict__ secb, int Q, int N, int S) {
    int r = blockIdx.x * 4 + (threadIdx.x >> 6);
    int lane = threadIdx.x & 63;
    if (r >= Q + N + S) return;
    const float* src; unsigned short* dst; int row;
    if (r < Q) { src = que; dst = queb; row = r; }
    else if (r < Q + N) { src = sen; dst = senb; row = r - Q; }
    else { src = sec; dst = secb; row = r - Q - N; }
    const float4* p = (const float4*)(src + (size_t)row * D);
    float4 v = p[lane];
    float ss = v.x * v.x + v.y * v.y + v.z * v.z + v.w * v.w;
    #pragma unroll
    for (int m = 1; m < 64; m <<= 1) ss += __shfl_xor(ss, m);
    float rn = rsqrtf(ss);
    ushort4 o;
    o.x = f2bf(v.x * rn); o.y = f2bf(v.y * rn); o.z = f2bf(v.z * rn); o.w = f2bf(v.w * rn);
    *(ushort4*)(dst + (size_t)row * D + lane * 4) = o;
}

// Mega kernel. blockIdx.y == 0: SQ path (x < Q/128 active, no LDS, reg-direct MFMA).
// blockIdx.y >= 1: QS 128x128 tile, BK=32 double-buffered, counted vmcnt pipeline.
__global__ __launch_bounds__(256, 4)
void qs_sq(const unsigned short* __restrict__ queb, const unsigned short* __restrict__ senb,
           const unsigned short* __restrict__ secb,
           const int* __restrict__ pidq, const int* __restrict__ pidn,
           const int* __restrict__ sidx, int Q,
           float* __restrict__ partial, int* __restrict__ cnt, float* __restrict__ pos_s,
           float* __restrict__ sq_all, float* __restrict__ sq_pos, int* __restrict__ sq_m,
           float* __restrict__ simq) {
    __shared__ unsigned short As[2][128 * 32];
    __shared__ unsigned short Bs[2][128 * 32];
    __shared__ int pqs[128];
    __shared__ int pns[128];
    __shared__ float sums[2][128];
    __shared__ int lcnt;
    __shared__ int lq[PBUF];
    __shared__ float lsv[PBUF];

    const int tid = threadIdx.x;
    const int lane = tid & 63;
    const int cl = lane & 15;
    const int g = lane >> 4;
    const int wid = tid >> 6;

    if (blockIdx.y == 0) {
        // ---------------- SQ path: 64 sections x 128 questions, fragments from global ----------------
        if ((int)blockIdx.x >= (Q >> 7)) return;
        const int q0 = blockIdx.x * 128;
        const int qw = q0 + wid * 32;
        f32x4 acc[4][2];
        #pragma unroll
        for (int si = 0; si < 4; ++si)
            #pragma unroll
            for (int qi = 0; qi < 2; ++qi)
                acc[si][qi] = (f32x4){0.f, 0.f, 0.f, 0.f};
        const unsigned short* abase = secb + (size_t)cl * D + g * 8;
        const unsigned short* bbase = queb + (size_t)(qw + cl) * D + g * 8;
        #pragma unroll
        for (int kk = 0; kk < 8; ++kk) {
            const int k0 = kk * 32;
            bf16x8_t af[4], bq[2];
            #pragma unroll
            for (int si = 0; si < 4; ++si)
                af[si] = *(const bf16x8_t*)(abase + si * 16 * D + k0);
            #pragma unroll
            for (int qi = 0; qi < 2; ++qi)
                bq[qi] = *(const bf16x8_t*)(bbase + qi * 16 * D + k0);
            #pragma unroll
            for (int si = 0; si < 4; ++si)
                #pragma unroll
                for (int qi = 0; qi < 2; ++qi)
                    acc[si][qi] = __builtin_amdgcn_mfma_f32_16x16x32_bf16(af[si], bq[qi], acc[si][qi], 0, 0, 0);
        }
        int sidxv[2];
        sidxv[0] = sidx[qw + cl];
        sidxv[1] = sidx[qw + 16 + cl];
        #pragma unroll
        for (int si = 0; si < 4; ++si) {
            float pa[4] = {0.f, 0.f, 0.f, 0.f};
            #pragma unroll
            for (int qi = 0; qi < 2; ++qi) {
                #pragma unroll
                for (int j = 0; j < 4; ++j) {
                    int srow = si * 16 + g * 4 + j;
                    float sv = acc[si][qi][j] * INV_TAU;
                    float e = __expf(sv);
                    pa[j] += e;
                    if (sidxv[qi] == srow) {
                        int q = qw + qi * 16 + cl;
                        simq[q] = sv;
                        atomicAdd(&sq_pos[srow], e);
                        atomicAdd(&sq_m[srow], 1);
                    }
                }
            }
            #pragma unroll
            for (int j = 0; j < 4; ++j) {
                float a = pa[j];
                #pragma unroll
                for (int msk = 1; msk < 16; msk <<= 1) a += __shfl_xor(a, msk);
                if (cl == 0) atomicAdd(&sq_all[si * 16 + g * 4 + j], a);
            }
        }
        return;
    }

    // ---------------- QS path ----------------
    const int wr = wid >> 1, wc = wid & 1;
    const int n0 = blockIdx.x * 128;
    const int q0 = (blockIdx.y - 1) * 128;

    if (tid < 128) pqs[tid] = pidq[q0 + tid];
    else           pns[tid - 128] = pidn[n0 + tid - 128];
    if (tid == 0) lcnt = 0;
    __syncthreads();   // pid visible + vmcnt drained before counted waits

    // Staging: tile = 128 rows x 32 el = 512 16B-chunks per matrix; wave w covers
    // chunks [(2w+j)*64, +64) for j=0,1. Linear layout (no swizzle needed at BK=32).
    int cid0 = (2 * wid) * 64 + lane;
    int cid1 = (2 * wid + 1) * 64 + lane;
    const unsigned short* qa0 = queb + (size_t)(q0 + (cid0 >> 2)) * D + (cid0 & 3) * 8;
    const unsigned short* qa1 = queb + (size_t)(q0 + (cid1 >> 2)) * D + (cid1 & 3) * 8;
    const unsigned short* sb0 = senb + (size_t)(n0 + (cid0 >> 2)) * D + (cid0 & 3) * 8;
    const unsigned short* sb1 = senb + (size_t)(n0 + (cid1 >> 2)) * D + (cid1 & 3) * 8;
    const int ld0 = (2 * wid) * 512;       // wave-uniform LDS element base
    const int ld1 = (2 * wid + 1) * 512;

#define STAGE(buf, k0) do { \
    GLOAD16(qa0 + (k0), &As[buf][ld0]); \
    GLOAD16(qa1 + (k0), &As[buf][ld1]); \
    GLOAD16(sb0 + (k0), &Bs[buf][ld0]); \
    GLOAD16(sb1 + (k0), &Bs[buf][ld1]); \
} while (0)

    f32x4 acc[4][4];
    #pragma unroll
    for (int m = 0; m < 4; ++m)
        #pragma unroll
        for (int n = 0; n < 4; ++n)
            acc[m][n] = (f32x4){0.f, 0.f, 0.f, 0.f};

    STAGE(0, 0);
    #pragma unroll
    for (int ks = 0; ks < 8; ++ks) {
        const int cur = ks & 1;
        if (ks < 7) {
            STAGE(cur ^ 1, (ks + 1) * 32);
            asm volatile("s_waitcnt vmcnt(4)" ::: "memory");
        } else {
            asm volatile("s_waitcnt vmcnt(0)" ::: "memory");
        }
        __builtin_amdgcn_s_barrier();
        bf16x8_t af[4], bg[4];
        #pragma unroll
        for (int m = 0; m < 4; ++m) {
            int r = wr * 64 + m * 16 + cl;
            af[m] = *(const bf16x8_t*)&As[cur][r * 32 + g * 8];
        }
        #pragma unroll
        for (int n = 0; n < 4; ++n) {
            int r = wc * 64 + n * 16 + cl;
            bg[n] = *(const bf16x8_t*)&Bs[cur][r * 32 + g * 8];
        }
        #pragma unroll
        for (int m = 0; m < 4; ++m)
            #pragma unroll
            for (int n = 0; n < 4; ++n)
                acc[m][n] = __builtin_amdgcn_mfma_f32_16x16x32_bf16(af[m], bg[n], acc[m][n], 0, 0, 0);
        if (ks < 7) __builtin_amdgcn_s_barrier();
    }
#undef STAGE

    // Epilogue: exp + per-row sums (block-local) + LDS positive capture.
    #pragma unroll
    for (int m = 0; m < 4; ++m) {
        float se[4] = {0.f, 0.f, 0.f, 0.f};
        int pqr[4];
        #pragma unroll
        for (int j = 0; j < 4; ++j) pqr[j] = pqs[wr * 64 + m * 16 + g * 4 + j];
        #pragma unroll
        for (int n = 0; n < 4; ++n) {
            const int pcol = pns[wc * 64 + n * 16 + cl];
            #pragma unroll
            for (int j = 0; j < 4; ++j) {
                float s = acc[m][n][j] * INV_TAU;
                float e = __expf(s);
                se[j] += e;
                if (pqr[j] == pcol) {
                    int li = atomicAdd(&lcnt, 1);
                    if (li < PBUF) { lq[li] = q0 + wr * 64 + m * 16 + g * 4 + j; lsv[li] = s; }
                }
            }
        }
        #pragma unroll
        for (int j = 0; j < 4; ++j) {
            float a = se[j];
            #pragma unroll
            for (int msk = 1; msk < 16; msk <<= 1) a += __shfl_xor(a, msk);
            if (cl == 0) sums[wc][wr * 64 + m * 16 + g * 4 + j] = a;
        }
    }
    __syncthreads();
    if (tid < 128)
        partial[(size_t)blockIdx.x * Q + q0 + tid] = sums[0][tid] + sums[1][tid];
    int nc = lcnt < PBUF ? lcnt : PBUF;
    for (int i = tid; i < nc; i += 256) {
        int q = lq[i];
        int idx = atomicAdd(&cnt[q], 1);
        if (idx < CAP) pos_s[(size_t)q * CAP + idx] = lsv[i];
    }
}

// Finish: wave per question. Reduces row partials, computes g + QS terms, and the
// per-question SQ term. Block partials -> bpart (no contended atomics).
__global__ __launch_bounds__(256)
void finish(const float* __restrict__ partial, int NB,
            const int* __restrict__ cnt, const float* __restrict__ pos_s,
            const int* __restrict__ sidx, const float* __restrict__ simq,
            const float* __restrict__ sq_all, const float* __restrict__ sq_pos,
            const int* __restrict__ sq_m,
            const int* __restrict__ npp, int Qn, int Ntot,
            float* __restrict__ bpart) {
    __shared__ float fred[4][4];
    const int tid = threadIdx.x, lane = tid & 63, wid = tid >> 6;
    const int q = blockIdx.x * 4 + wid;

    float Sa = 0.f;
    for (int nb = lane; nb < NB; nb += 64) Sa += partial[(size_t)nb * Qn + q];
    #pragma unroll
    for (int m = 1; m < 64; m <<= 1) Sa += __shfl_xor(Sa, m);

    int M = cnt[q];
    int mc = M < CAP ? M : CAP;
    float s = 0.f, e = 0.f;
    if (lane < mc) { s = pos_s[(size_t)q * CAP + lane]; e = __expf(s); }
    float Sp = e;
    #pragma unroll
    for (int m = 1; m < 64; m <<= 1) Sp += __shfl_xor(Sp, m);

    int Nn = Ntot - M;
    int P = npp[0];
    float eta_p = 1.0f / (float)(P > 1 ? P : 1);
    float eta_m = 1.0f - eta_p;
    float Mf = (float)(M > 1 ? M : 1);
    float Nnf = (float)(Nn > 1 ? Nn : 1);
    float gg = fmaxf(((Sa - Sp) / Nnf - eta_p * Sp / Mf) / eta_m, __expf(-INV_TAU));
    float c = (float)Nn * gg;

    float contrib = (lane < mc) ? (s - __logf(e + c)) : 0.f;
    #pragma unroll
    for (int m = 1; m < 64; m <<= 1) contrib += __shfl_xor(contrib, m);

    if (lane == 0) {
        float qs_num = 0.f, qs_cnt = 0.f, sq_num = 0.f, sq_cnt = 0.f;
        if (M > 0 && Nn > 0) { qs_num = contrib; qs_cnt = (float)M; }
        int sct = sidx[q];
        int Mq = sq_m[sct];
        if (Mq > 0 && (Qn - Mq) > 0) {
            float sv = simq[q];
            float sumneg = sq_all[sct] - sq_pos[sct];
            sq_num = sv - __logf(__expf(sv) + sumneg);
            sq_cnt = 1.f;
        }
        fred[wid][0] = qs_num; fred[wid][1] = qs_cnt;
        fred[wid][2] = sq_num; fred[wid][3] = sq_cnt;
    }
    __syncthreads();
    if (tid < 4) {
        float v = fred[0][tid] + fred[1][tid] + fred[2][tid] + fred[3][tid];
        bpart[(size_t)blockIdx.x * 4 + tid] = v;
    }
}

__global__ void combine2(const float* __restrict__ bpart, int nblk, float* __restrict__ out) {
    __shared__ float r2[4][4];
    const int tid = threadIdx.x, lane = tid & 63, wid = tid >> 6;
    float v[4] = {0.f, 0.f, 0.f, 0.f};
    for (int i = tid; i < nblk; i += 256) {
        #pragma unroll
        for (int c2 = 0; c2 < 4; ++c2) v[c2] += bpart[(size_t)i * 4 + c2];
    }
    #pragma unroll
    for (int m = 1; m < 64; m <<= 1)
        #pragma unroll
        for (int c2 = 0; c2 < 4; ++c2) v[c2] += __shfl_xor(v[c2], m);
    if (lane == 0) {
        #pragma unroll
        for (int c2 = 0; c2 < 4; ++c2) r2[wid][c2] = v[c2];
    }
    __syncthreads();
    if (tid == 0) {
        float qs_num = r2[0][0] + r2[1][0] + r2[2][0] + r2[3][0];
        float qs_cnt = r2[0][1] + r2[1][1] + r2[2][1] + r2[3][1];
        float sq_num = r2[0][2] + r2[1][2] + r2[2][2] + r2[3][2];
        float sq_cnt = r2[0][3] + r2[1][3] + r2[2][3] + r2[3][3];
        float qs = qs_cnt > 0.f ? -qs_num / qs_cnt : 0.f;
        float sq = sq_cnt > 0.f ? -sq_num / sq_cnt : 0.f;
        out[0] = qs + sq;
    }
}

extern "C" void kernel_launch(void* const* d_in, const int* in_sizes, int n_in,
                              void* d_out, int out_size, void* d_ws, size_t ws_size,
                              hipStream_t stream) {
    const float* sec = (const float*)d_in[1];
    const float* que = (const float*)d_in[2];
    const float* sen = (const float*)d_in[3];
    const int* pidq = (const int*)d_in[4];
    const int* sidx = (const int*)d_in[5];
    const int* pidn = (const int*)d_in[6];
    const int* npp = (const int*)d_in[7];
    const int S = in_sizes[1] / D;
    const int Q = in_sizes[2] / D;
    const int N = in_sizes[3] / D;
    const int NB = N / 128;
    const int FBLK = Q / 4;

    char* p = (char*)d_ws;
    unsigned short* queb = (unsigned short*)p; p += (size_t)Q * D * 2;
    unsigned short* senb = (unsigned short*)p; p += (size_t)N * D * 2;
    unsigned short* secb = (unsigned short*)p; p += (size_t)S * D * 2;
    float* simq = (float*)p; p += (size_t)Q * 4;
    float* pos_s = (float*)p; p += (size_t)Q * CAP * 4;
    float* partial = (float*)p; p += (size_t)NB * Q * 4;
    float* bpart = (float*)p; p += (size_t)FBLK * 4 * 4;
    char* z0 = p;
    int* cnt = (int*)p; p += (size_t)Q * 4;
    float* sq_all = (float*)p; p += (size_t)S * 4;
    float* sq_pos = (float*)p; p += (size_t)S * 4;
    int* sq_m = (int*)p; p += (size_t)S * 4;
    size_t zbytes = (size_t)(p - z0);

    hipMemsetAsync(z0, 0, zbytes, stream);
    norm_all<<<(Q + N + S + 3) / 4, 256, 0, stream>>>(que, sen, sec, queb, senb, secb, Q, N, S);
    qs_sq<<<dim3(NB, Q / 128 + 1), 256, 0, stream>>>(queb, senb, secb, pidq, pidn, sidx, Q,
                                                     partial, cnt, pos_s,
                                                     sq_all, sq_pos, sq_m, simq);
    finish<<<FBLK, 256, 0, stream>>>(partial, NB, cnt, pos_s, sidx, simq,
                                     sq_all, sq_pos, sq_m, npp, Q, N, bpart);
    combine2<<<1, 256, 0, stream>>>(bpart, FBLK, (float*)d_out);
}